// Round 3
// baseline (385.992 us; speedup 1.0000x reference)
//
#include <hip/hip_runtime.h>
#include <hip/hip_fp16.h>

#define NN 256
#define VV 25
#define TT 128
#define CIN 64
#define CO 64
#define RR 9
#define HH4 18
#define HH5 6
#define ROWS (VV * TT)   // 3200
#define BLK 1024

__device__ __forceinline__ float silu_f(float v) {
  return __fdividef(v, 1.0f + __expf(-v));
}

__global__ __launch_bounds__(BLK, 4) void k_fused(
    const float* __restrict__ x, const float* __restrict__ A,
    const float* __restrict__ W1, const float* __restrict__ b1,
    const float* __restrict__ W2, const float* __restrict__ b2,
    const float* __restrict__ W3, const float* __restrict__ b3,
    const float* __restrict__ W4a, const float* __restrict__ b4a,
    const float* __restrict__ W4b, const float* __restrict__ b4b,
    const float* __restrict__ W5a, const float* __restrict__ b5a,
    const float* __restrict__ W5b, const float* __restrict__ b5b,
    float* __restrict__ out) {
  const int n = blockIdx.x;
  const int tid = threadIdx.x;

  __shared__ __half  x3s[ROWS * 10];       // 64000 B, row stride 10 halves (odd half2 stride -> conflict-free)
  __shared__ float   mPart[VV][2][2 * RR]; // 3600 B   per-(v, half-wave) partial sums of x1,x2 rows
  __shared__ float   m12[2][VV][12];       // 2400 B   m1, m2
  __shared__ __half2 h2s[VV * VV * 5];     // 12500 B  h
  __shared__ __half2 a5s[ROWS * 3];        // 38400 B  silu(agg@W5a+b5a)

  const float* xn = x + (size_t)n * ROWS * CIN;

  // ---------------- phase 1: stream x, project to x1/x2/x3 ----------------
  for (int r = tid; r < ROWS; r += BLK) {
    float a1[RR], a2[RR], a3[RR];
    #pragma unroll
    for (int j = 0; j < RR; ++j) { a1[j] = 0.f; a2[j] = 0.f; a3[j] = b3[j]; }
    const float4* src = (const float4*)(xn + (size_t)r * CIN);
    #pragma unroll
    for (int hf = 0; hf < 2; ++hf) {
      float4 buf[8];
      #pragma unroll
      for (int k = 0; k < 8; ++k) buf[k] = src[hf * 8 + k];
      const float* xr = (const float*)buf;
      #pragma unroll
      for (int c = 0; c < 32; ++c) {
        const int cc = hf * 32 + c;
        const float xv = xr[c];
        #pragma unroll
        for (int j = 0; j < RR; ++j) {
          a1[j] = fmaf(xv, W1[cc * RR + j], a1[j]);
          a2[j] = fmaf(xv, W2[cc * RR + j], a2[j]);
          a3[j] = fmaf(xv, W3[cc * RR + j], a3[j]);
        }
      }
    }
    // x3 row -> LDS (half, stride 10)
    __half2* xrow = (__half2*)(x3s + r * 10);
    xrow[0] = __floats2half2_rn(a3[0], a3[1]);
    xrow[1] = __floats2half2_rn(a3[2], a3[3]);
    xrow[2] = __floats2half2_rn(a3[4], a3[5]);
    xrow[3] = __floats2half2_rn(a3[6], a3[7]);
    xrow[4] = __floats2half2_rn(a3[8], 0.f);
    // wave butterfly sum of a1,a2 (64 rows per wave, all same v)
    #pragma unroll
    for (int j = 0; j < RR; ++j) {
      float s1 = a1[j], s2 = a2[j];
      #pragma unroll
      for (int m = 1; m < 64; m <<= 1) {
        s1 += __shfl_xor(s1, m);
        s2 += __shfl_xor(s2, m);
      }
      a1[j] = s1; a2[j] = s2;
    }
    const int v = r >> 7;               // wave-uniform
    const int part = (tid >> 6) & 1;    // which half of the 128 t-rows
    if ((tid & 63) == 0) {
      #pragma unroll
      for (int j = 0; j < RR; ++j) {
        mPart[v][part][j] = a1[j];
        mPart[v][part][j + RR] = a2[j];
      }
    }
  }
  __syncthreads();

  // ---------------- phase 2a: temporal means ----------------
  if (tid < 2 * VV * RR) {
    const int which = tid >= VV * RR;
    const int idx = which ? tid - VV * RR : tid;
    const int v = idx / RR, j = idx - v * RR;
    const float* bb = which ? b2 : b1;
    m12[which][v][j] = bb[j] +
        (mPart[v][0][j + which * RR] + mPart[v][1][j + which * RR]) * (1.f / TT);
  }
  __syncthreads();

  // ---------------- phase 2b: h = silu MLP(m1[u]-m2[v]) + A ----------------
  if (tid < VV * VV) {
    const int u = tid / VV, v2 = tid - u * VV;
    float rel[RR];
    #pragma unroll
    for (int j = 0; j < RR; ++j) rel[j] = m12[0][u][j] - m12[1][v2][j];
    float t1[HH4];
    #pragma unroll
    for (int k = 0; k < HH4; ++k) {
      float s = b4a[k];
      #pragma unroll
      for (int j = 0; j < RR; ++j) s = fmaf(rel[j], W4a[j * HH4 + k], s);
      t1[k] = silu_f(s);
    }
    const float av = A[u * VV + v2];
    float hc[RR];
    #pragma unroll
    for (int j = 0; j < RR; ++j) {
      float s = b4b[j];
      #pragma unroll
      for (int k = 0; k < HH4; ++k) s = fmaf(t1[k], W4b[k * RR + j], s);
      hc[j] = silu_f(s) + av;
    }
    __half2* hp = h2s + tid * 5;
    hp[0] = __floats2half2_rn(hc[0], hc[1]);
    hp[1] = __floats2half2_rn(hc[2], hc[3]);
    hp[2] = __floats2half2_rn(hc[4], hc[5]);
    hp[3] = __floats2half2_rn(hc[6], hc[7]);
    hp[4] = __floats2half2_rn(hc[8], 0.f);
  }
  __syncthreads();

  // ---------------- phase 3a: agg over v + 9->6 layer ----------------
  for (int p = tid; p < ROWS; p += BLK) {
    const int u = p >> 7, t = p & (TT - 1);
    const __half2* xrow = (const __half2*)x3s + t * 5;
    const __half2* hrow = h2s + u * VV * 5;
    __half2 c0 = __floats2half2_rn(0.f, 0.f), c1 = c0, c2 = c0, c3 = c0, c4 = c0;
    #pragma unroll
    for (int v = 0; v < VV; ++v) {
      const __half2* xv = xrow + v * TT * 5;
      const __half2* hv = hrow + v * 5;
      c0 = __hfma2(hv[0], xv[0], c0);
      c1 = __hfma2(hv[1], xv[1], c1);
      c2 = __hfma2(hv[2], xv[2], c2);
      c3 = __hfma2(hv[3], xv[3], c3);
      c4 = __hfma2(hv[4], xv[4], c4);
    }
    float ag[RR];
    ag[0] = __low2float(c0); ag[1] = __high2float(c0);
    ag[2] = __low2float(c1); ag[3] = __high2float(c1);
    ag[4] = __low2float(c2); ag[5] = __high2float(c2);
    ag[6] = __low2float(c3); ag[7] = __high2float(c3);
    ag[8] = __low2float(c4);
    float a5v[HH5];
    #pragma unroll
    for (int k = 0; k < HH5; ++k) {
      float s = b5a[k];
      #pragma unroll
      for (int j = 0; j < RR; ++j) s = fmaf(ag[j], W5a[j * HH5 + k], s);
      a5v[k] = silu_f(s);
    }
    a5s[p * 3 + 0] = __floats2half2_rn(a5v[0], a5v[1]);
    a5s[p * 3 + 1] = __floats2half2_rn(a5v[2], a5v[3]);
    a5s[p * 3 + 2] = __floats2half2_rn(a5v[4], a5v[5]);
  }
  __syncthreads();

  // ---------------- phase 3b: 6->64 epilogue, coalesced stores ----------------
  const int cq = (tid & 15) * 4;
  float4 wb[HH5];
  #pragma unroll
  for (int k = 0; k < HH5; ++k) wb[k] = *(const float4*)(W5b + k * CO + cq);
  const float4 bb4 = *(const float4*)(b5b + cq);
  float* obase = out + (size_t)n * ROWS * CO;
  for (int it = 0; it < ROWS / 64; ++it) {
    const int q = it * 64 + (tid >> 4);
    const __half2 p01 = a5s[q * 3 + 0];
    const __half2 p23 = a5s[q * 3 + 1];
    const __half2 p45 = a5s[q * 3 + 2];
    const float a0 = __low2float(p01), a1f = __high2float(p01);
    const float a2f = __low2float(p23), a3f = __high2float(p23);
    const float a4f = __low2float(p45), a5f = __high2float(p45);
    float4 y;
    y.x = silu_f(bb4.x + a0 * wb[0].x + a1f * wb[1].x + a2f * wb[2].x +
                 a3f * wb[3].x + a4f * wb[4].x + a5f * wb[5].x);
    y.y = silu_f(bb4.y + a0 * wb[0].y + a1f * wb[1].y + a2f * wb[2].y +
                 a3f * wb[3].y + a4f * wb[4].y + a5f * wb[5].y);
    y.z = silu_f(bb4.z + a0 * wb[0].z + a1f * wb[1].z + a2f * wb[2].z +
                 a3f * wb[3].z + a4f * wb[4].z + a5f * wb[5].z);
    y.w = silu_f(bb4.w + a0 * wb[0].w + a1f * wb[1].w + a2f * wb[2].w +
                 a3f * wb[3].w + a4f * wb[4].w + a5f * wb[5].w);
    *(float4*)(obase + (size_t)q * CO + cq) = y;
  }
}

extern "C" void kernel_launch(void* const* d_in, const int* in_sizes, int n_in,
                              void* d_out, int out_size, void* d_ws, size_t ws_size,
                              hipStream_t stream) {
  const float* x   = (const float*)d_in[0];
  const float* A   = (const float*)d_in[1];
  const float* W1  = (const float*)d_in[2];
  const float* b1  = (const float*)d_in[3];
  const float* W2  = (const float*)d_in[4];
  const float* b2  = (const float*)d_in[5];
  const float* W3  = (const float*)d_in[6];
  const float* b3  = (const float*)d_in[7];
  const float* W4a = (const float*)d_in[8];
  const float* b4a = (const float*)d_in[9];
  const float* W4b = (const float*)d_in[10];
  const float* b4b = (const float*)d_in[11];
  const float* W5a = (const float*)d_in[12];
  const float* b5a = (const float*)d_in[13];
  const float* W5b = (const float*)d_in[14];
  const float* b5b = (const float*)d_in[15];
  float* out = (float*)d_out;

  hipLaunchKernelGGL(k_fused, dim3(NN), dim3(BLK), 0, stream,
                     x, A, W1, b1, W2, b2, W3, b3,
                     W4a, b4a, W4b, b4b, W5a, b5a, W5b, b5b, out);
}

// Round 4
// 162.221 us; speedup vs baseline: 2.3794x; 2.3794x over previous
//
#include <hip/hip_runtime.h>
#include <hip/hip_fp16.h>

#define NN 256
#define VV 25
#define TT 128
#define CIN 64
#define CO 64
#define RR 9
#define HH4 18
#define HH5 6
#define TQ 32
#define NT 4

typedef unsigned int uint;

__device__ __forceinline__ float silu_f(float v) {
  return __fdividef(v, 1.0f + __expf(-v));
}
__device__ __forceinline__ __half2 u2h(uint u) {
  union { uint x; __half2 h; } c; c.x = u; return c.h;
}
__device__ __forceinline__ uint h2u(__half2 h) {
  union { __half2 h; uint x; } c; c.h = h; return c.x;
}

// ---------------------------------------------------------------------------
// k1: per (n,v): coalesced stage of x tile -> LDS transpose; x3 = x@W3+b3
// (12 halves/row, [n][tq][v][t][12] global layout); xm = column sums of x
// computed from registers (no extra LDS pass).
// ---------------------------------------------------------------------------
__global__ __launch_bounds__(128, 2) void k1_proj(
    const float* __restrict__ x, const float* __restrict__ W3,
    const float* __restrict__ b3, uint* __restrict__ x3g,
    float* __restrict__ xm) {
  const int blk = blockIdx.x;            // n*V + v
  const int n = blk / VV, v = blk - n * VV;
  const int tid = threadIdx.x;
  __shared__ __align__(16) float xt[TT * 68];   // stride 68: b128 conflict-free
  __shared__ __align__(16) float xmp[2][64];

  const float4* src = (const float4*)(x + (size_t)blk * TT * CIN);
  float4 r[16];
  #pragma unroll
  for (int k = 0; k < 16; ++k) r[k] = src[k * 128 + tid];
  #pragma unroll
  for (int k = 0; k < 16; ++k) {
    const int idx = k * 128 + tid;
    const int t = idx >> 4, c = (idx & 15) * 4;
    *(float4*)(xt + t * 68 + c) = r[k];
  }
  // column partial sums from registers: lane covers 16 rows, channels (tid&15)*4..+3
  float4 cs = r[0];
  #pragma unroll
  for (int k = 1; k < 16; ++k) {
    cs.x += r[k].x; cs.y += r[k].y; cs.z += r[k].z; cs.w += r[k].w;
  }
  #pragma unroll
  for (int m = 16; m < 64; m <<= 1) {
    cs.x += __shfl_xor(cs.x, m); cs.y += __shfl_xor(cs.y, m);
    cs.z += __shfl_xor(cs.z, m); cs.w += __shfl_xor(cs.w, m);
  }
  if ((tid & 63) < 16) *(float4*)(&xmp[tid >> 6][(tid & 15) * 4]) = cs;
  __syncthreads();
  if (tid < 64) xm[(size_t)blk * 64 + tid] = xmp[0][tid] + xmp[1][tid];

  // x3 row for t = tid via b128 LDS reads
  float acc[RR];
  #pragma unroll
  for (int j = 0; j < RR; ++j) acc[j] = b3[j];
  const float* xrow = xt + tid * 68;
  #pragma unroll
  for (int c4 = 0; c4 < 16; ++c4) {
    const float4 xv = *(const float4*)(xrow + c4 * 4);
    #pragma unroll
    for (int j = 0; j < RR; ++j) {
      acc[j] = fmaf(xv.x, W3[(c4 * 4 + 0) * RR + j], acc[j]);
      acc[j] = fmaf(xv.y, W3[(c4 * 4 + 1) * RR + j], acc[j]);
      acc[j] = fmaf(xv.z, W3[(c4 * 4 + 2) * RR + j], acc[j]);
      acc[j] = fmaf(xv.w, W3[(c4 * 4 + 3) * RR + j], acc[j]);
    }
  }
  uint w0 = h2u(__floats2half2_rn(acc[0], acc[1]));
  uint w1 = h2u(__floats2half2_rn(acc[2], acc[3]));
  uint w2 = h2u(__floats2half2_rn(acc[4], acc[5]));
  uint w3 = h2u(__floats2half2_rn(acc[6], acc[7]));
  uint w4 = h2u(__floats2half2_rn(acc[8], 0.f));
  uint* dst = x3g +
      ((((size_t)n * NT + (tid >> 5)) * VV + v) * TQ + (tid & 31)) * 6;
  ((uint2*)dst)[0] = make_uint2(w0, w1);
  ((uint2*)dst)[1] = make_uint2(w2, w3);
  ((uint2*)dst)[2] = make_uint2(w4, 0u);
}

// ---------------------------------------------------------------------------
// k2: per n: means from xm, rel MLP (9->18->9), + A -> h ([n][u][v][12 halves])
// ---------------------------------------------------------------------------
__global__ __launch_bounds__(128) void k2_h(
    const float* __restrict__ xm, const float* __restrict__ A,
    const float* __restrict__ W1, const float* __restrict__ b1,
    const float* __restrict__ W2, const float* __restrict__ b2,
    const float* __restrict__ W4a, const float* __restrict__ b4a,
    const float* __restrict__ W4b, const float* __restrict__ b4b,
    uint* __restrict__ h2g) {
  const int n = blockIdx.x;
  const int tid = threadIdx.x;
  __shared__ float m1[VV][RR + 1];
  __shared__ float m2[VV][RR + 1];
  const float* xmn = xm + (size_t)n * VV * CIN;
  for (int i = tid; i < 2 * VV * RR; i += 128) {
    const int which = (i >= VV * RR);
    const int idx = which ? i - VV * RR : i;
    const int v = idx / RR, c = idx - v * RR;
    const float* W = which ? W2 : W1;
    const float* b = which ? b2 : b1;
    const float* row = xmn + v * CIN;
    float s = 0.f;
    #pragma unroll
    for (int k = 0; k < CIN; ++k) s = fmaf(row[k], W[k * RR + c], s);
    s = s * (1.0f / TT) + b[c];
    if (which) m2[v][c] = s; else m1[v][c] = s;
  }
  __syncthreads();
  for (int p = tid; p < VV * VV; p += 128) {
    const int u = p / VV, v2 = p - u * VV;
    float rel[RR];
    #pragma unroll
    for (int j = 0; j < RR; ++j) rel[j] = m1[u][j] - m2[v2][j];
    float t1[HH4];
    #pragma unroll
    for (int k = 0; k < HH4; ++k) {
      float s = b4a[k];
      #pragma unroll
      for (int j = 0; j < RR; ++j) s = fmaf(rel[j], W4a[j * HH4 + k], s);
      t1[k] = silu_f(s);
    }
    const float av = A[u * VV + v2];
    float hc[RR];
    #pragma unroll
    for (int j = 0; j < RR; ++j) {
      float s = b4b[j];
      #pragma unroll
      for (int k = 0; k < HH4; ++k) s = fmaf(t1[k], W4b[k * RR + j], s);
      hc[j] = silu_f(s) + av;
    }
    uint* hp = h2g + ((size_t)n * VV * VV + p) * 6;
    hp[0] = h2u(__floats2half2_rn(hc[0], hc[1]));
    hp[1] = h2u(__floats2half2_rn(hc[2], hc[3]));
    hp[2] = h2u(__floats2half2_rn(hc[4], hc[5]));
    hp[3] = h2u(__floats2half2_rn(hc[6], hc[7]));
    hp[4] = h2u(__floats2half2_rn(hc[8], 0.f));
    hp[5] = 0u;
  }
}

// ---------------------------------------------------------------------------
// k3: per (n,tq): stage x3 tile (contiguous) + h to LDS; agg over v (half2,
// b64-pair LDS reads); 9->6 silu -> a5s; coalesced 6->64 silu epilogue.
// ---------------------------------------------------------------------------
__global__ __launch_bounds__(256, 3) void k3_out(
    const uint* __restrict__ x3g, const uint* __restrict__ h2g,
    const float* __restrict__ W5a, const float* __restrict__ b5a,
    const float* __restrict__ W5b, const float* __restrict__ b5b,
    float* __restrict__ out) {
  const int bid = blockIdx.x;           // n*NT + tq
  const int n = bid >> 2, tq = bid & 3;
  const int tid = threadIdx.x;
  __shared__ __align__(16) uint x3s[VV * TQ * 6];   // 19200 B
  __shared__ __align__(16) uint h2s[VV * VV * 6];   // 15000 B
  __shared__ __align__(16) uint a5s[VV * TQ * 3];   //  9600 B

  const uint* xsrc = x3g + (size_t)bid * (VV * TQ * 6);
  for (int i = tid; i < (VV * TQ * 6) / 4; i += 256)
    ((uint4*)x3s)[i] = ((const uint4*)xsrc)[i];
  const uint* hsrc = h2g + (size_t)n * (VV * VV * 6);
  for (int i = tid; i < VV * VV * 6; i += 256) h2s[i] = hsrc[i];
  __syncthreads();

  // C1: agg + 9->6 silu
  for (int p = tid; p < VV * TQ; p += 256) {
    const int u = p >> 5, t = p & 31;
    const uint* xr = x3s + t * 6;
    const uint* hr = h2s + u * VV * 6;
    __half2 c0 = u2h(0u), c1 = c0, c2 = c0, c3 = c0, c4 = c0;
    #pragma unroll 5
    for (int v2 = 0; v2 < VV; ++v2) {
      const uint2 xa = *(const uint2*)(xr + v2 * 192);
      const uint2 xb = *(const uint2*)(xr + v2 * 192 + 2);
      const uint  xc = xr[v2 * 192 + 4];
      const uint2 ha = *(const uint2*)(hr + v2 * 6);
      const uint2 hb = *(const uint2*)(hr + v2 * 6 + 2);
      const uint  hc = hr[v2 * 6 + 4];
      c0 = __hfma2(u2h(ha.x), u2h(xa.x), c0);
      c1 = __hfma2(u2h(ha.y), u2h(xa.y), c1);
      c2 = __hfma2(u2h(hb.x), u2h(xb.x), c2);
      c3 = __hfma2(u2h(hb.y), u2h(xb.y), c3);
      c4 = __hfma2(u2h(hc),   u2h(xc),   c4);
    }
    float ag[RR];
    ag[0] = __low2float(c0); ag[1] = __high2float(c0);
    ag[2] = __low2float(c1); ag[3] = __high2float(c1);
    ag[4] = __low2float(c2); ag[5] = __high2float(c2);
    ag[6] = __low2float(c3); ag[7] = __high2float(c3);
    ag[8] = __low2float(c4);
    float a5v[HH5];
    #pragma unroll
    for (int k = 0; k < HH5; ++k) {
      float s = b5a[k];
      #pragma unroll
      for (int j = 0; j < RR; ++j) s = fmaf(ag[j], W5a[j * HH5 + k], s);
      a5v[k] = silu_f(s);
    }
    a5s[p * 3 + 0] = h2u(__floats2half2_rn(a5v[0], a5v[1]));
    a5s[p * 3 + 1] = h2u(__floats2half2_rn(a5v[2], a5v[3]));
    a5s[p * 3 + 2] = h2u(__floats2half2_rn(a5v[4], a5v[5]));
  }
  __syncthreads();

  // C2: 16 lanes per row, 4 channels each; 1KB-coalesced stores
  const int cq = (tid & 15) * 4;
  float4 wb[HH5];
  #pragma unroll
  for (int k = 0; k < HH5; ++k) wb[k] = *(const float4*)(W5b + k * CO + cq);
  const float4 bb = *(const float4*)(b5b + cq);
  for (int it = 0; it < (VV * TQ) / 16; ++it) {
    const int q = it * 16 + (tid >> 4);
    const int u = q >> 5, t = q & 31;
    const __half2 p01 = u2h(a5s[q * 3 + 0]);
    const __half2 p23 = u2h(a5s[q * 3 + 1]);
    const __half2 p45 = u2h(a5s[q * 3 + 2]);
    const float a0 = __low2float(p01), a1 = __high2float(p01);
    const float a2 = __low2float(p23), a3 = __high2float(p23);
    const float a4 = __low2float(p45), a5 = __high2float(p45);
    float4 y;
    y.x = silu_f(bb.x + a0 * wb[0].x + a1 * wb[1].x + a2 * wb[2].x +
                 a3 * wb[3].x + a4 * wb[4].x + a5 * wb[5].x);
    y.y = silu_f(bb.y + a0 * wb[0].y + a1 * wb[1].y + a2 * wb[2].y +
                 a3 * wb[3].y + a4 * wb[4].y + a5 * wb[5].y);
    y.z = silu_f(bb.z + a0 * wb[0].z + a1 * wb[1].z + a2 * wb[2].z +
                 a3 * wb[3].z + a4 * wb[4].z + a5 * wb[5].z);
    y.w = silu_f(bb.w + a0 * wb[0].w + a1 * wb[1].w + a2 * wb[2].w +
                 a3 * wb[3].w + a4 * wb[4].w + a5 * wb[5].w);
    float* orow = out +
        ((size_t)(n * VV + u) * TT + tq * TQ + t) * CO + cq;
    *(float4*)orow = y;
  }
}

extern "C" void kernel_launch(void* const* d_in, const int* in_sizes, int n_in,
                              void* d_out, int out_size, void* d_ws, size_t ws_size,
                              hipStream_t stream) {
  const float* x   = (const float*)d_in[0];
  const float* A   = (const float*)d_in[1];
  const float* W1  = (const float*)d_in[2];
  const float* b1  = (const float*)d_in[3];
  const float* W2  = (const float*)d_in[4];
  const float* b2  = (const float*)d_in[5];
  const float* W3  = (const float*)d_in[6];
  const float* b3  = (const float*)d_in[7];
  const float* W4a = (const float*)d_in[8];
  const float* b4a = (const float*)d_in[9];
  const float* W4b = (const float*)d_in[10];
  const float* b4b = (const float*)d_in[11];
  const float* W5a = (const float*)d_in[12];
  const float* b5a = (const float*)d_in[13];
  const float* W5b = (const float*)d_in[14];
  const float* b5b = (const float*)d_in[15];
  float* out = (float*)d_out;

  char* ws = (char*)d_ws;
  uint*  x3g = (uint*)ws;                        // 19,660,800 B
  float* xm  = (float*)(ws + 19660800);          //  1,638,400 B
  uint*  h2g = (uint*)(ws + 19660800 + 1638400); //  3,840,000 B

  hipLaunchKernelGGL(k1_proj, dim3(NN * VV), dim3(128), 0, stream,
                     x, W3, b3, x3g, xm);
  hipLaunchKernelGGL(k2_h, dim3(NN), dim3(128), 0, stream,
                     xm, A, W1, b1, W2, b2, W4a, b4a, W4b, b4b, h2g);
  hipLaunchKernelGGL(k3_out, dim3(NN * NT), dim3(256), 0, stream,
                     x3g, h2g, W5a, b5a, W5b, b5b, out);
}